// Round 8
// baseline (537.500 us; speedup 1.0000x reference)
//
#include <hip/hip_runtime.h>

#define NN 8192
#define FF 256
#define PST 136   // P LDS row stride in halves (128 + 8 pad, 16B-aligned)

typedef _Float16 h8 __attribute__((ext_vector_type(8)));
typedef _Float16 h4 __attribute__((ext_vector_type(4)));
typedef float    f4 __attribute__((ext_vector_type(4)));
typedef int      i4v __attribute__((ext_vector_type(4)));

// monotone float<->uint encoding for atomicMax on fp32
__device__ __forceinline__ unsigned fenc(float x) {
  unsigned u = __float_as_uint(x);
  return (u & 0x80000000u) ? ~u : (u | 0x80000000u);
}
__device__ __forceinline__ float fdec(unsigned e) {
  unsigned u = (e & 0x80000000u) ? (e ^ 0x80000000u) : ~e;
  return __uint_as_float(u);
}

// lgkm-only barrier (CK block_sync_lds pattern): publishes LDS writes without
// draining vmem (plain __syncthreads emits s_waitcnt vmcnt(0)).
__device__ __forceinline__ void sync_lds() {
  __builtin_amdgcn_s_waitcnt(0xc07f);   // lgkmcnt(0), vmcnt/expcnt ignored
  __builtin_amdgcn_s_barrier();
}

// ---------------- Kernel 1: Wh = h@W (fp32 vector), s1, s2(f16), wfrag -------
// grid 512 x 256 thr. Block = 16 rows of h = half of k-tile (blockIdx>>1).
// wfrag[(kt*16+n)*512 + lane*8 + j] = Wh[kt*32 + (lane>>4)*8 + j][n*16 + (lane&15)]
__global__ __launch_bounds__(256) void k_wh(
    const float* __restrict__ h, const float* __restrict__ W,
    const float* __restrict__ a, _Float16* __restrict__ wfrag,
    float* __restrict__ s1, _Float16* __restrict__ s2h,
    unsigned* __restrict__ s2maxe) {
  __shared__ float hs[16 * 256];        // 16 KB
  __shared__ _Float16 whs[16 * 264];    // 8.25 KB
  const int t = threadIdx.x;
  const int r0 = blockIdx.x * 16;
#pragma unroll
  for (int i = 0; i < 4; ++i) {
    int idx = i * 1024 + t * 4;
    *(f4*)&hs[idx] = *(const f4*)&h[(size_t)r0 * 256 + idx];
  }
  __syncthreads();
  const int lane = t & 63;
  const int wv = t >> 6;        // 0..3
  const int rg = wv * 4;
  const int c4 = lane * 4;
  float acc[4][4];
#pragma unroll
  for (int i = 0; i < 4; ++i)
#pragma unroll
    for (int k = 0; k < 4; ++k) acc[i][k] = 0.f;
  f4 w[8];
#pragma unroll
  for (int i = 0; i < 8; ++i) w[i] = *(const f4*)&W[i * 256 + c4];
  for (int f = 0; f < 256; f += 8) {
    f4 nw[8];
    if (f < 248) {
#pragma unroll
      for (int i = 0; i < 8; ++i) nw[i] = *(const f4*)&W[(f + 8 + i) * 256 + c4];
    }
#pragma unroll
    for (int i = 0; i < 4; ++i) {
      f4 h0 = *(const f4*)&hs[(rg + i) * 256 + f];
      f4 h1 = *(const f4*)&hs[(rg + i) * 256 + f + 4];
#pragma unroll
      for (int k = 0; k < 4; ++k)
        acc[i][k] += h0[0]*w[0][k] + h0[1]*w[1][k] + h0[2]*w[2][k] + h0[3]*w[3][k]
                   + h1[0]*w[4][k] + h1[1]*w[5][k] + h1[2]*w[6][k] + h1[3]*w[7][k];
    }
    if (f < 248) {
#pragma unroll
      for (int i = 0; i < 8; ++i) w[i] = nw[i];
    }
  }
  float a1v[4], a2v[4];
#pragma unroll
  for (int k = 0; k < 4; ++k) { a1v[k] = a[c4 + k]; a2v[k] = a[256 + c4 + k]; }
#pragma unroll
  for (int i = 0; i < 4; ++i) {
    h4 hh;
    float p1 = 0.f, p2 = 0.f;
#pragma unroll
    for (int k = 0; k < 4; ++k) {
      hh[k] = (_Float16)acc[i][k];
      p1 += acc[i][k] * a1v[k];
      p2 += acc[i][k] * a2v[k];
    }
    *(h4*)&whs[(rg + i) * 264 + c4] = hh;
#pragma unroll
    for (int off = 32; off; off >>= 1) {
      p1 += __shfl_xor(p1, off);
      p2 += __shfl_xor(p2, off);
    }
    if (lane == 0) {
      const int r = r0 + rg + i;
      s1[r] = p1;
      s2h[r] = (_Float16)p2;
      atomicMax(s2maxe, fenc(p2));
    }
  }
  __syncthreads();
  {
    const int kt = blockIdx.x >> 1;
    const int hb = blockIdx.x & 1;
    const int lp = hb * 32 + (t & 31);
    const int kb = ((t & 31) >> 4) * 8;
    const int m16e = t & 15;
#pragma unroll
    for (int p = 0; p < 2; ++p) {
      const int n = (t >> 5) + p * 8;
      h8 v;
#pragma unroll
      for (int j = 0; j < 8; ++j) v[j] = whs[(kb + j) * 264 + n * 16 + m16e];
      *(h8*)&wfrag[(((size_t)kt * 16 + n) << 9) + lp * 8] = v;
    }
  }
}

// ---------------- Kernel 2: fused attention ----------------------------------
// grid 512 = (rt 0..255) x (kh 0..1); 512 thr; LB(512,4) -> 2 blocks/CU.
// Block: 32 rows x 256 cols x 4096 k. PROLOGUE: lane packs its adjacency slice
// (row srow, k = m16*8 + 128p, p=0..31) into 8 VGPR dwords via a 16-deep
// pipelined nontemporal stream (HBM-saturating burst). MAIN LOOP: the ONLY
// vmem is the B-frag stream, ping-ponged at full-period distance -> every
// MFMA B-wait is on period-old L2 loads; adj/HBM never touches the loop.
__global__ __launch_bounds__(512, 4) void k_gat(
    const int* __restrict__ adj, const _Float16* __restrict__ wfrag,
    const float* __restrict__ s1g, const _Float16* __restrict__ s2h,
    const unsigned* __restrict__ s2maxe,
    float* __restrict__ o0, float* __restrict__ o1,
    float* __restrict__ lbuf) {
  __shared__ _Float16 P[2][32 * PST];   // 17 KB
  __shared__ _Float16 s2l[4096];        // 8 KB
  const int t = threadIdx.x;
  const int lane = t & 63;
  const int w = t >> 6;          // 0..7: score rows 4w..4w+3; cols [32w,32w+32)
  const int q = lane >> 4;       // 0..3
  const int m16 = lane & 15;
  const int rt = (int)blockIdx.x >> 1;
  const int kh = (int)blockIdx.x & 1;
  const int r0 = rt * 32;

  ((h8*)s2l)[t] = ((const h8*)(s2h + kh * 4096))[t];   // stage kh-half s2

  const int srow = 4 * w + q;                // this lane's score row (local)
  const float s2m = fdec(*s2maxe);
  const float s1r = s1g[r0 + srow];
  const float u0 = s1r + s2m;
  const float mi = fmaxf(u0, 0.2f * u0);     // >= leaky(s1r+s2[j]) for all j
  const float s1mi = s1r - mi;

  // ---- prologue: pack adj bits (32 bytes/lane) through a 16-deep pipeline
  const int* adjp = adj + (size_t)(r0 + srow) * NN + kh * 4096 + m16 * 8;
  unsigned bits[8] = {0, 0, 0, 0, 0, 0, 0, 0};
  {
    i4v buf[16];
#pragma unroll
    for (int i = 0; i < 16; ++i)
      buf[i] = __builtin_nontemporal_load(
          (const i4v*)(adjp + (i >> 1) * 128 + (i & 1) * 4));
#pragma unroll
    for (int i = 0; i < 64; ++i) {
      const i4v v = buf[i & 15];
      if (i + 16 < 64)
        buf[i & 15] = __builtin_nontemporal_load(
            (const i4v*)(adjp + ((i + 16) >> 1) * 128 + ((i + 16) & 1) * 4));
      const unsigned nib = (unsigned)(v[0] > 0) | ((unsigned)(v[1] > 0) << 1) |
                           ((unsigned)(v[2] > 0) << 2) | ((unsigned)(v[3] > 0) << 3);
      bits[i >> 3] |= nib << ((((i >> 1) & 3) << 3) + ((i & 1) << 2));
    }
  }

  f4 acc[2][2];
#pragma unroll
  for (int m = 0; m < 2; ++m)
#pragma unroll
    for (int n = 0; n < 2; ++n)
#pragma unroll
      for (int e = 0; e < 4; ++e) acc[m][n][e] = 0.f;
  float lsum = 0.f;

  __syncthreads();   // s2l ready (bits already packed; queue empty anyway)

  // preload B(0)
  h8 bb[2][8];
  {
    const _Float16* wfb =
        wfrag + ((((size_t)(kh * 128)) * 16 + 2 * w) << 9) + lane * 8;
#pragma unroll
    for (int ks = 0; ks < 4; ++ks) {
      bb[0][2 * ks]     = *(const h8*)(wfb + ks * 8192);
      bb[0][2 * ks + 1] = *(const h8*)(wfb + ks * 8192 + 512);
    }
  }

  auto period = [&](int p, h8 (&bcur)[8], h8 (&bnxt)[8]) {
    // (1) B prefetch for p+1 (only vmem in the loop; consumed next period)
    if (p < 31) {
      const _Float16* wfn =
          wfrag + ((((size_t)(kh * 128 + (p + 1) * 4)) * 16 + 2 * w) << 9) + lane * 8;
#pragma unroll
      for (int ks = 0; ks < 4; ++ks) {
        bnxt[2 * ks]     = *(const h8*)(wfn + ks * 8192);
        bnxt[2 * ks + 1] = *(const h8*)(wfn + ks * 8192 + 512);
      }
    }
    // (2) scores from registers (bits) + LDS (s2): zero vmem
    const unsigned byte = (bits[p >> 2] >> ((p & 3) << 3)) & 0xffu;
    const h8 s2c = *(const h8*)&s2l[p * 128 + m16 * 8];
    h8 pa;
#pragma unroll
    for (int j = 0; j < 8; ++j) {
      const float s2v = (float)s2c[j];
      const float u = s1r + s2v;
      const float arg = s1mi + s2v - 0.8f * fminf(u, 0.f);
      const float pv = (byte & (1u << j)) ? __expf(arg) : 0.f;
      lsum += pv;
      pa[j] = (_Float16)pv;
    }
    _Float16* Pb = &P[p & 1][0];
    *(h8*)&Pb[srow * PST + m16 * 8] = pa;
    // (3) publish P without draining vmem
    sync_lds();
    // (4) MFMA with bcur (loaded a full period ago; wait = vmcnt(8))
#pragma unroll
    for (int ks = 0; ks < 4; ++ks) {
      const h8 A0 = *(const h8*)&Pb[m16 * PST + ks * 32 + q * 8];
      const h8 A1 = *(const h8*)&Pb[(16 + m16) * PST + ks * 32 + q * 8];
      acc[0][0] = __builtin_amdgcn_mfma_f32_16x16x32_f16(A0, bcur[2*ks],   acc[0][0], 0, 0, 0);
      acc[0][1] = __builtin_amdgcn_mfma_f32_16x16x32_f16(A0, bcur[2*ks+1], acc[0][1], 0, 0, 0);
      acc[1][0] = __builtin_amdgcn_mfma_f32_16x16x32_f16(A1, bcur[2*ks],   acc[1][0], 0, 0, 0);
      acc[1][1] = __builtin_amdgcn_mfma_f32_16x16x32_f16(A1, bcur[2*ks+1], acc[1][1], 0, 0, 0);
    }
  };

  for (int pp = 0; pp < 16; ++pp) {
    period(2 * pp,     bb[0], bb[1]);
    period(2 * pp + 1, bb[1], bb[0]);
  }

  // partial softmax denominator (row srow): reduce over the 16 m16 lanes
  lsum += __shfl_xor(lsum, 1);
  lsum += __shfl_xor(lsum, 2);
  lsum += __shfl_xor(lsum, 4);
  lsum += __shfl_xor(lsum, 8);
  if (m16 == 0) lbuf[kh * NN + r0 + srow] = lsum;

  // partial O: plain stores (each element written once per kh)
  float* ob = kh ? o1 : o0;
#pragma unroll
  for (int m = 0; m < 2; ++m)
#pragma unroll
    for (int n = 0; n < 2; ++n)
#pragma unroll
      for (int v = 0; v < 4; ++v)
        ob[(size_t)(r0 + m * 16 + q * 4 + v) * FF + w * 32 + n * 16 + m16] =
            acc[m][n][v];
}

// ---------------- Kernel 3: combine halves, normalize, elu -------------------
__global__ __launch_bounds__(256) void k_fin(
    float* __restrict__ out, const float* __restrict__ o1,
    const float* __restrict__ lbuf) {
  const int t = threadIdx.x;
  const int row = blockIdx.x * 16 + (t >> 4);
  const int c0 = (t & 15) * 16;
  const float linv = 1.0f / (lbuf[row] + lbuf[NN + row]);
#pragma unroll
  for (int i = 0; i < 4; ++i) {
    f4 v0 = *(const f4*)&out[(size_t)row * FF + c0 + i * 4];
    f4 v1 = *(const f4*)&o1[(size_t)row * FF + c0 + i * 4];
    f4 o;
#pragma unroll
    for (int e = 0; e < 4; ++e) {
      float x = (v0[e] + v1[e]) * linv;
      o[e] = (x > 0.f) ? x : (__expf(x) - 1.f);
    }
    *(f4*)&out[(size_t)row * FF + c0 + i * 4] = o;
  }
}

extern "C" void kernel_launch(void* const* d_in, const int* in_sizes, int n_in,
                              void* d_out, int out_size, void* d_ws, size_t ws_size,
                              hipStream_t stream) {
  const float* h   = (const float*)d_in[0];
  const int*   adj = (const int*)d_in[1];
  const float* W   = (const float*)d_in[2];
  const float* a   = (const float*)d_in[3];
  float* out = (float*)d_out;

  char* ws = (char*)d_ws;
  _Float16* wfrag = (_Float16*)ws;                                // 4 MB
  float*    o1    = (float*)(ws + (4u << 20));                    // 8 MB (kh=1 partial)
  float*    lbuf  = (float*)(ws + (12u << 20));                   // 64 KB (2 x 8192 f32)
  unsigned* s2me  = (unsigned*)(ws + (12u << 20) + 65536);        // 4 B (+60 pad)
  float*    s1    = (float*)(ws + (12u << 20) + 65600);           // 32 KB
  _Float16* s2h   = (_Float16*)(ws + (12u << 20) + 65600 + 32768);// 16 KB

  hipMemsetAsync(s2me, 0, 4, stream);   // fenc-domain -inf
  k_wh<<<512, 256, 0, stream>>>(h, W, a, wfrag, s1, s2h, s2me);
  k_gat<<<512, 512, 0, stream>>>(adj, wfrag, s1, s2h, s2me, out, o1, lbuf);
  k_fin<<<512, 256, 0, stream>>>(out, o1, lbuf);
}

// Round 9
// 514.863 us; speedup vs baseline: 1.0440x; 1.0440x over previous
//
#include <hip/hip_runtime.h>

#define NN 8192
#define FF 256
#define PST 136   // P LDS row stride in halves (128 + 8 pad)

typedef _Float16 h8 __attribute__((ext_vector_type(8)));
typedef _Float16 h4 __attribute__((ext_vector_type(4)));
typedef float    f4 __attribute__((ext_vector_type(4)));
typedef int      i4v __attribute__((ext_vector_type(4)));

__device__ __forceinline__ unsigned fenc(float x) {
  unsigned u = __float_as_uint(x);
  return (u & 0x80000000u) ? ~u : (u | 0x80000000u);
}
__device__ __forceinline__ float fdec(unsigned e) {
  unsigned u = (e & 0x80000000u) ? (e ^ 0x80000000u) : ~e;
  return __uint_as_float(u);
}

// lgkm-only barrier: publishes LDS writes without draining vmem.
__device__ __forceinline__ void sync_lds() {
  __builtin_amdgcn_s_waitcnt(0xc07f);
  __builtin_amdgcn_s_barrier();
}

// ---------------- Kernel 1: Wh = h@W (fp32 vector), s1, s2(f16), wfrag -------
// grid 512 x 256 thr. Block = 16 rows of h = half of k-tile (blockIdx>>1).
// wfrag[(kt*16+n)*512 + lane*8 + j] = Wh[kt*32 + (lane>>4)*8 + j][n*16 + (lane&15)]
__global__ __launch_bounds__(256) void k_wh(
    const float* __restrict__ h, const float* __restrict__ W,
    const float* __restrict__ a, _Float16* __restrict__ wfrag,
    float* __restrict__ s1, _Float16* __restrict__ s2h,
    unsigned* __restrict__ s2maxe) {
  __shared__ float hs[16 * 256];
  __shared__ _Float16 whs[16 * 264];
  const int t = threadIdx.x;
  const int r0 = blockIdx.x * 16;
#pragma unroll
  for (int i = 0; i < 4; ++i) {
    int idx = i * 1024 + t * 4;
    *(f4*)&hs[idx] = *(const f4*)&h[(size_t)r0 * 256 + idx];
  }
  __syncthreads();
  const int lane = t & 63;
  const int wv = t >> 6;
  const int rg = wv * 4;
  const int c4 = lane * 4;
  float acc[4][4];
#pragma unroll
  for (int i = 0; i < 4; ++i)
#pragma unroll
    for (int k = 0; k < 4; ++k) acc[i][k] = 0.f;
  f4 w[8];
#pragma unroll
  for (int i = 0; i < 8; ++i) w[i] = *(const f4*)&W[i * 256 + c4];
  for (int f = 0; f < 256; f += 8) {
    f4 nw[8];
    if (f < 248) {
#pragma unroll
      for (int i = 0; i < 8; ++i) nw[i] = *(const f4*)&W[(f + 8 + i) * 256 + c4];
    }
#pragma unroll
    for (int i = 0; i < 4; ++i) {
      f4 h0 = *(const f4*)&hs[(rg + i) * 256 + f];
      f4 h1 = *(const f4*)&hs[(rg + i) * 256 + f + 4];
#pragma unroll
      for (int k = 0; k < 4; ++k)
        acc[i][k] += h0[0]*w[0][k] + h0[1]*w[1][k] + h0[2]*w[2][k] + h0[3]*w[3][k]
                   + h1[0]*w[4][k] + h1[1]*w[5][k] + h1[2]*w[6][k] + h1[3]*w[7][k];
    }
    if (f < 248) {
#pragma unroll
      for (int i = 0; i < 8; ++i) w[i] = nw[i];
    }
  }
  float a1v[4], a2v[4];
#pragma unroll
  for (int k = 0; k < 4; ++k) { a1v[k] = a[c4 + k]; a2v[k] = a[256 + c4 + k]; }
#pragma unroll
  for (int i = 0; i < 4; ++i) {
    h4 hh;
    float p1 = 0.f, p2 = 0.f;
#pragma unroll
    for (int k = 0; k < 4; ++k) {
      hh[k] = (_Float16)acc[i][k];
      p1 += acc[i][k] * a1v[k];
      p2 += acc[i][k] * a2v[k];
    }
    *(h4*)&whs[(rg + i) * 264 + c4] = hh;
#pragma unroll
    for (int off = 32; off; off >>= 1) {
      p1 += __shfl_xor(p1, off);
      p2 += __shfl_xor(p2, off);
    }
    if (lane == 0) {
      const int r = r0 + rg + i;
      s1[r] = p1;
      s2h[r] = (_Float16)p2;
      atomicMax(s2maxe, fenc(p2));
    }
  }
  __syncthreads();
  {
    const int kt = blockIdx.x >> 1;
    const int hb = blockIdx.x & 1;
    const int lp = hb * 32 + (t & 31);
    const int kb = ((t & 31) >> 4) * 8;
    const int m16e = t & 15;
#pragma unroll
    for (int p = 0; p < 2; ++p) {
      const int n = (t >> 5) + p * 8;
      h8 v;
#pragma unroll
      for (int j = 0; j < 8; ++j) v[j] = whs[(kb + j) * 264 + n * 16 + m16e];
      *(h8*)&wfrag[(((size_t)kt * 16 + n) << 9) + lp * 8] = v;
    }
  }
}

// ---------------- Kernel 2: fused attention, 128-row blocks ------------------
// grid 256 = (rt 0..63) x (kq 0..3); 512 thr; 1 block/CU.
// Block: 128 rows x 256 cols x 2048 k (its k-quarter). B-traffic = 1 MB/block
// -> 256 MB total (4x cut vs 32-row blocks); adj loads NONTEMPORAL so wfrag
// stays L2-resident. Per 128-k period: B(p) issued first (L2, aged ~scores),
// adj(p+1) after (HBM, aged a full period); scores -> P dbuf; lgkm barrier;
// 64 MFMA/wave. Partial O via plain stores (o[kq]), combined in k_fin.
__global__ __launch_bounds__(512, 2) void k_gat(
    const int* __restrict__ adj, const _Float16* __restrict__ wfrag,
    const float* __restrict__ s1g, const _Float16* __restrict__ s2h,
    const unsigned* __restrict__ s2maxe,
    float* __restrict__ o0, float* __restrict__ o1,
    float* __restrict__ o2, float* __restrict__ o3,
    float* __restrict__ lbuf) {
  __shared__ _Float16 P[2][128 * PST];  // 69.6 KB
  __shared__ _Float16 s2l[2048];        // 4 KB
  const int t = threadIdx.x;
  const int lane = t & 63;
  const int w = t >> 6;          // 0..7: score rows [16w,16w+16); cols [32w,32w+32)
  const int q = lane >> 4;       // 0..3
  const int m16 = lane & 15;
  const int rt = (int)blockIdx.x >> 2;
  const int kq = (int)blockIdx.x & 3;
  const int r0 = rt * 128;

  if (t < 256) ((h8*)s2l)[t] = ((const h8*)(s2h + kq * 2048))[t];

  const int rloc = w * 16 + m16;             // this lane's score row (local)
  const float s2m = fdec(*s2maxe);
  const float s1r = s1g[r0 + rloc];
  const float u0 = s1r + s2m;
  const float mi = fmaxf(u0, 0.2f * u0);     // >= leaky(s1r+s2[j]) for all j
  const float s1mi = s1r - mi;

  f4 acc[8][2];
#pragma unroll
  for (int mt = 0; mt < 8; ++mt)
#pragma unroll
    for (int n = 0; n < 2; ++n)
#pragma unroll
      for (int e = 0; e < 4; ++e) acc[mt][n][e] = 0.f;
  float lsum = 0.f;

  const int* adjp = adj + (size_t)(r0 + rloc) * NN + kq * 2048 + q * 8;
  __syncthreads();   // s2l ready

  // preload adj for period 0 (nontemporal: don't evict wfrag from L2)
  i4v adjc[8], adjn[8];
#pragma unroll
  for (int ks = 0; ks < 4; ++ks) {
    adjc[2 * ks]     = __builtin_nontemporal_load((const i4v*)(adjp + ks * 32));
    adjc[2 * ks + 1] = __builtin_nontemporal_load((const i4v*)(adjp + ks * 32 + 4));
  }

  for (int p = 0; p < 16; ++p) {
    const int kb = kq * 64 + p * 4;   // global k-tile base
    // (1) B(p): 8 L2-resident loads, oldest vmem of the period
    h8 bb[8];
#pragma unroll
    for (int ks = 0; ks < 4; ++ks) {
      const _Float16* wfb =
          wfrag + (((size_t)(kb + ks) * 16 + 2 * w) << 9) + lane * 8;
      bb[2 * ks]     = *(const h8*)(wfb);
      bb[2 * ks + 1] = *(const h8*)(wfb + 512);
    }
    // (2) adj(p+1): HBM, consumed a full period later; newer than B in queue
    if (p < 15) {
#pragma unroll
      for (int ks = 0; ks < 4; ++ks) {
        adjn[2 * ks]     = __builtin_nontemporal_load(
            (const i4v*)(adjp + (p + 1) * 128 + ks * 32));
        adjn[2 * ks + 1] = __builtin_nontemporal_load(
            (const i4v*)(adjp + (p + 1) * 128 + ks * 32 + 4));
      }
    }
    // (3) scores: 32 cells/thread, row rloc, k = ks*32+q*8+j
    _Float16* Pb = &P[p & 1][0];
#pragma unroll
    for (int ks = 0; ks < 4; ++ks) {
      const h8 s2c = *(const h8*)&s2l[p * 128 + ks * 32 + q * 8];
      const i4v a0 = adjc[2 * ks];
      const i4v a1 = adjc[2 * ks + 1];
      h8 pa;
#pragma unroll
      for (int j = 0; j < 8; ++j) {
        const float s2v = (float)s2c[j];
        const float u = s1r + s2v;
        const float arg = s1mi + s2v - 0.8f * fminf(u, 0.f);
        const int msk = (j < 4) ? a0[j] : a1[j - 4];
        const float pv = (msk > 0) ? __expf(arg) : 0.f;
        lsum += pv;
        pa[j] = (_Float16)pv;
      }
      *(h8*)&Pb[rloc * PST + ks * 32 + q * 8] = pa;
    }
    // (4) publish P without draining vmem (adj/B stay in flight)
    sync_lds();
    // (5) MFMA: 4 ks x 8 mt x 2 n; A from LDS, B aged ~score-phase
#pragma unroll
    for (int ks = 0; ks < 4; ++ks) {
#pragma unroll
      for (int mt = 0; mt < 8; ++mt) {
        const h8 A = *(const h8*)&Pb[(mt * 16 + m16) * PST + ks * 32 + q * 8];
        acc[mt][0] = __builtin_amdgcn_mfma_f32_16x16x32_f16(A, bb[2*ks],   acc[mt][0], 0, 0, 0);
        acc[mt][1] = __builtin_amdgcn_mfma_f32_16x16x32_f16(A, bb[2*ks+1], acc[mt][1], 0, 0, 0);
      }
    }
#pragma unroll
    for (int i = 0; i < 8; ++i) adjc[i] = adjn[i];
  }

  // partial denominator for row rloc: reduce over the 4 q-threads
  lsum += __shfl_xor(lsum, 16);
  lsum += __shfl_xor(lsum, 32);
  if (q == 0) lbuf[kq * NN + r0 + rloc] = lsum;

  // partial O: plain stores (C layout: col=lane&15, row=q*4+reg)
  float* ob = (kq == 0) ? o0 : (kq == 1) ? o1 : (kq == 2) ? o2 : o3;
#pragma unroll
  for (int mt = 0; mt < 8; ++mt)
#pragma unroll
    for (int n = 0; n < 2; ++n)
#pragma unroll
      for (int v = 0; v < 4; ++v)
        ob[(size_t)(r0 + mt * 16 + q * 4 + v) * FF + w * 32 + n * 16 + m16] =
            acc[mt][n][v];
}

// ---------------- Kernel 3: combine quarters, normalize, elu -----------------
__global__ __launch_bounds__(256) void k_fin(
    float* __restrict__ out, const float* __restrict__ o1,
    const float* __restrict__ o2, const float* __restrict__ o3,
    const float* __restrict__ lbuf) {
  const int t = threadIdx.x;
  const int row = blockIdx.x * 16 + (t >> 4);
  const int c0 = (t & 15) * 16;
  const float linv = 1.0f / (lbuf[row] + lbuf[NN + row] +
                             lbuf[2 * NN + row] + lbuf[3 * NN + row]);
#pragma unroll
  for (int i = 0; i < 4; ++i) {
    const size_t off = (size_t)row * FF + c0 + i * 4;
    f4 v0 = *(const f4*)&out[off];
    f4 v1 = *(const f4*)&o1[off];
    f4 v2 = *(const f4*)&o2[off];
    f4 v3 = *(const f4*)&o3[off];
    f4 o;
#pragma unroll
    for (int e = 0; e < 4; ++e) {
      float x = (v0[e] + v1[e] + v2[e] + v3[e]) * linv;
      o[e] = (x > 0.f) ? x : (__expf(x) - 1.f);
    }
    *(f4*)&out[off] = o;
  }
}

extern "C" void kernel_launch(void* const* d_in, const int* in_sizes, int n_in,
                              void* d_out, int out_size, void* d_ws, size_t ws_size,
                              hipStream_t stream) {
  const float* h   = (const float*)d_in[0];
  const int*   adj = (const int*)d_in[1];
  const float* W   = (const float*)d_in[2];
  const float* a   = (const float*)d_in[3];
  float* out = (float*)d_out;

  char* ws = (char*)d_ws;
  _Float16* wfrag = (_Float16*)ws;                                // 4 MB
  float*    o1    = (float*)(ws + (4u << 20));                    // 8 MB
  float*    o2    = (float*)(ws + (12u << 20));                   // 8 MB
  float*    o3    = (float*)(ws + (20u << 20));                   // 8 MB
  float*    lbuf  = (float*)(ws + (28u << 20));                   // 128 KB
  unsigned* s2me  = (unsigned*)(ws + (28u << 20) + 131072);       // 4 B (+60 pad)
  float*    s1    = (float*)(ws + (28u << 20) + 131136);          // 32 KB
  _Float16* s2h   = (_Float16*)(ws + (28u << 20) + 131136 + 32768); // 16 KB

  hipMemsetAsync(s2me, 0, 4, stream);   // fenc-domain -inf
  k_wh<<<512, 256, 0, stream>>>(h, W, a, wfrag, s1, s2h, s2me);
  k_gat<<<256, 512, 0, stream>>>(adj, wfrag, s1, s2h, s2me,
                                 out, o1, o2, o3, lbuf);
  k_fin<<<512, 256, 0, stream>>>(out, o1, o2, o3, lbuf);
}